// Round 1
// baseline (815.946 us; speedup 1.0000x reference)
//
#include <hip/hip_runtime.h>

// Symbolic LeNet: quantize -> symconv1(sort25+fold) -> symconv2(sort200+fold) -> MLP+softmax.
// All symbol math must be bit-exact; only the final MLP is float.

// ---------------- K0: lut prep (transpose conv_lut to u16, add/relu to u16) --------------
__global__ __launch_bounds__(256) void k_prep(const int* __restrict__ conv_lut,
                                              const int* __restrict__ add_lut,
                                              const int* __restrict__ relu_lut,
                                              unsigned short* __restrict__ lutT,
                                              unsigned short* __restrict__ add16,
                                              unsigned short* __restrict__ relu16) {
  int id = blockIdx.x * 256 + threadIdx.x;   // 0..262143
  int s = id >> 9, c = id & 511;
  lutT[c * 512 + s] = (unsigned short)conv_lut[id];   // lutT[col][sym]
  add16[id] = (unsigned short)add_lut[id];
  if (id < 512) relu16[id] = (unsigned short)relu_lut[id];
}

// ---------------- K1: quantize (exact argmin, first-index ties) --------------------------
__global__ __launch_bounds__(256) void k_quant(const float* __restrict__ x,
                                               const float* __restrict__ cen,
                                               unsigned short* __restrict__ sym) {
  __shared__ float cs[512];
  int t = threadIdx.x;
  cs[t] = cen[t];
  cs[t + 256] = cen[t + 256];
  __syncthreads();
  int pix = blockIdx.x * 256 + t;            // grid exactly covers 2048*784
  float xv = x[pix];
  float bd = 1e30f;
  int bi = 0;
  #pragma unroll 8
  for (int j = 0; j < 512; ++j) {
    float d = fabsf(xv - cs[j]);
    if (d < bd) { bd = d; bi = j; }          // strict < keeps first index (jnp.argmin)
  }
  sym[pix] = (unsigned short)bi;
}

// ---------------- K2: symconv1 -----------------------------------------------------------
// pair-per-lane: block = (filter f, 64 windows). 25 taps -> reg bitonic-32 -> 24 serial folds.
__global__ __launch_bounds__(64) void k_conv1(const unsigned short* __restrict__ sym,
                                              const int* __restrict__ c1w,
                                              const unsigned short* __restrict__ lutT,
                                              const unsigned short* __restrict__ add16,
                                              const unsigned short* __restrict__ relu16,
                                              unsigned short* __restrict__ h1) {
  int bid = blockIdx.x;                 // 36864 = 8 f * 4608 chunks
  int f = bid / 4608;                   // uniform per block -> scalar c1w loads
  int chunk = bid - f * 4608;
  int W = chunk * 64 + threadIdx.x;     // window id 0..294911
  int i = W / 144;
  int p = W - i * 144;
  int wr = p / 12;
  int wc = p - wr * 12;
  const unsigned short* sp = sym + i * 784 + (2 * wr) * 28 + 2 * wc;

  unsigned v[32];
  #pragma unroll
  for (int kh = 0; kh < 5; ++kh)
    #pragma unroll
    for (int kw = 0; kw < 5; ++kw) {
      int l = kh * 5 + kw;
      unsigned sy = sp[kh * 28 + kw];
      int wt = c1w[l * 8 + f];                       // wave-uniform
      v[l] = lutT[((unsigned)wt << 9) + sy];         // uniform 1KB row, lane-varying col -> L1
    }
  #pragma unroll
  for (int l = 25; l < 32; ++l) v[l] = 0xFFFFFFFFu;  // sentinels sort to the end

  // bitonic-32 ascending, fully static indices -> registers
  #pragma unroll
  for (int k = 2; k <= 32; k <<= 1) {
    #pragma unroll
    for (int j = k >> 1; j > 0; j >>= 1) {
      #pragma unroll
      for (int a = 0; a < 32; ++a) {
        int b = a ^ j;
        if (b > a) {
          unsigned x0 = v[a], x1 = v[b];
          unsigned lo = min(x0, x1), hi = max(x0, x1);
          bool up = ((a & k) == 0);
          v[a] = up ? lo : hi;
          v[b] = up ? hi : lo;
        }
      }
    }
  }

  unsigned carry = v[0];
  #pragma unroll 1
  for (int l = 1; l < 25; ++l)
    carry = add16[(v[l] << 9) + carry];              // serial dependent gather chain
  h1[((i * 8 + f) * 12 + wr) * 12 + wc] = relu16[carry];  // channels-first for conv2 taps
}

// ---------------- K3: symconv2 -----------------------------------------------------------
// pair-per-lane; sort-200 via per-lane nibble histogram (512 bins x 4bit) in LDS,
// fold streams bins in ascending order (exact counting sort).
__global__ __launch_bounds__(64) void k_conv2(const unsigned short* __restrict__ h1,
                                              const int* __restrict__ c2w,
                                              const unsigned short* __restrict__ lutT,
                                              const unsigned short* __restrict__ add16,
                                              const unsigned short* __restrict__ relu16,
                                              unsigned short* __restrict__ h2) {
  __shared__ unsigned hist[64][64];      // [word][lane], bank = lane&31 -> conflict-free
  int lane = threadIdx.x;
  int bid = blockIdx.x;                  // 8192 = 16 f * 512 chunks
  int f = bid >> 9;                      // uniform per block
  int chunk = bid & 511;
  int W = chunk * 64 + lane;             // window id 0..32767 (2048 img * 16 windows)
  int i = W >> 4;
  int p = W & 15;
  int wr = p >> 2, wc = p & 3;

  #pragma unroll
  for (int w = 0; w < 64; ++w) hist[w][lane] = 0;

  // build histogram of the 200 products
  #pragma unroll 1
  for (int c = 0; c < 8; ++c) {
    int base = ((i * 8 + c) * 12 + 2 * wr) * 12 + 2 * wc;
    #pragma unroll
    for (int kh = 0; kh < 5; ++kh)
      #pragma unroll
      for (int kw = 0; kw < 5; ++kw) {
        unsigned sy = h1[base + kh * 12 + kw];
        int wt = c2w[(c * 25 + kh * 5 + kw) * 16 + f];   // wave-uniform
        unsigned prod = lutT[((unsigned)wt << 9) + sy];  // uniform row gather -> L1
        hist[prod >> 3][lane] += 1u << ((prod & 7) << 2);
      }
  }

  // stream fold in sorted order: 200 values total (counts sum to 200)
  int wptr = 0;
  unsigned cur = hist[0][lane];
  while (cur == 0 && wptr < 63) { ++wptr; cur = hist[wptr][lane]; }
  unsigned tz = __builtin_ctz(cur);
  unsigned nb = tz >> 2;
  unsigned carry = wptr * 8 + nb;        // first (smallest) value, no add_lut
  cur -= 1u << (nb << 2);
  #pragma unroll 1
  for (int j = 1; j < 200; ++j) {
    while (cur == 0 && wptr < 63) { ++wptr; cur = hist[wptr][lane]; }
    tz = __builtin_ctz(cur);
    nb = tz >> 2;
    unsigned s = wptr * 8 + nb;
    cur -= 1u << (nb << 2);
    carry = add16[(s << 9) + carry];     // serial dependent gather chain (199 deep)
  }
  h2[((i * 16 + f) * 4 + wr) * 4 + wc] = relu16[carry];  // [f][r][c] == flattened v order
}

// ---------------- K4: MLP + softmax ------------------------------------------------------
__global__ __launch_bounds__(128) void k_mlp(const unsigned short* __restrict__ h2,
                                             const float* __restrict__ cen,
                                             const float* __restrict__ W1,
                                             const float* __restrict__ W2,
                                             const float* __restrict__ W3,
                                             float* __restrict__ out) {
  __shared__ float v[256];
  __shared__ float a1[128];
  __shared__ float a2[64];
  __shared__ float lg[10];
  int i = blockIdx.x, t = threadIdx.x;
  v[t] = cen[h2[i * 256 + t]];
  v[t + 128] = cen[h2[i * 256 + t + 128]];
  __syncthreads();
  float acc = 0.f;
  #pragma unroll 4
  for (int k = 0; k < 256; ++k) acc = fmaf(W1[t * 256 + k], v[k], acc);
  a1[t] = fmaxf(acc, 0.f);
  __syncthreads();
  if (t < 64) {
    acc = 0.f;
    #pragma unroll 4
    for (int k = 0; k < 128; ++k) acc = fmaf(W2[t * 128 + k], a1[k], acc);
    a2[t] = fmaxf(acc, 0.f);
  }
  __syncthreads();
  if (t < 10) {
    acc = 0.f;
    #pragma unroll
    for (int k = 0; k < 64; ++k) acc = fmaf(W3[t * 64 + k], a2[k], acc);
    lg[t] = acc;
  }
  __syncthreads();
  if (t < 10) {
    float m = lg[0];
    #pragma unroll
    for (int j = 1; j < 10; ++j) m = fmaxf(m, lg[j]);
    float ssum = 0.f;
    #pragma unroll
    for (int j = 0; j < 10; ++j) ssum += expf(lg[j] - m);
    out[i * 10 + t] = expf(lg[t] - m) / ssum;
  }
}

// ---------------- launch -----------------------------------------------------------------
extern "C" void kernel_launch(void* const* d_in, const int* in_sizes, int n_in,
                              void* d_out, int out_size, void* d_ws, size_t ws_size,
                              hipStream_t stream) {
  const float* x    = (const float*)d_in[0];   // 2048*1*28*28
  const float* cen  = (const float*)d_in[1];   // 512
  const float* W1   = (const float*)d_in[2];   // 128*256
  const float* W2   = (const float*)d_in[3];   // 64*128
  const float* W3   = (const float*)d_in[4];   // 10*64
  const int* conv_lut = (const int*)d_in[5];   // 512*512
  const int* add_lut  = (const int*)d_in[6];   // 512*512
  const int* relu_lut = (const int*)d_in[7];   // 512
  const int* c1w = (const int*)d_in[8];        // 25*8
  const int* c2w = (const int*)d_in[9];        // 200*16
  float* out = (float*)d_out;

  char* ws = (char*)d_ws;
  unsigned short* lutT   = (unsigned short*)(ws);             // 512KB
  unsigned short* add16  = (unsigned short*)(ws + 524288);    // 512KB
  unsigned short* relu16 = (unsigned short*)(ws + 1048576);   // 1KB
  unsigned short* sym    = (unsigned short*)(ws + 1052672);   // 2048*784*2 = 3211264B
  unsigned short* h1     = (unsigned short*)(ws + 4263936);   // 2048*1152*2 = 4718592B
  unsigned short* h2     = (unsigned short*)(ws + 8982528);   // 2048*256*2 = 1048576B

  hipLaunchKernelGGL(k_prep,  dim3(1024),  dim3(256), 0, stream,
                     conv_lut, add_lut, relu_lut, lutT, add16, relu16);
  hipLaunchKernelGGL(k_quant, dim3(6272),  dim3(256), 0, stream, x, cen, sym);
  hipLaunchKernelGGL(k_conv1, dim3(36864), dim3(64),  0, stream,
                     sym, c1w, lutT, add16, relu16, h1);
  hipLaunchKernelGGL(k_conv2, dim3(8192),  dim3(64),  0, stream,
                     h1, c2w, lutT, add16, relu16, h2);
  hipLaunchKernelGGL(k_mlp,   dim3(2048),  dim3(128), 0, stream,
                     h2, cen, W1, W2, W3, out);
}